// Round 4
// baseline (381.777 us; speedup 1.0000x reference)
//
#include <hip/hip_runtime.h>
#include <hip/hip_bf16.h>

#define HW 16384
#define NPIX 65536
#define CC 256
#define NDIL 16
#define DFF 8
#define CATC 384
#define LNEPS 1e-3f

typedef short bf16x8 __attribute__((ext_vector_type(8)));
typedef float f32x4 __attribute__((ext_vector_type(4)));

__device__ __forceinline__ unsigned short f2bf(float f) {
    unsigned u = __builtin_bit_cast(unsigned, f);
    u += 0x7fffu + ((u >> 16) & 1u);
    return (unsigned short)(u >> 16);
}
__device__ __forceinline__ void bfpair(unsigned u, float& a, float& b) {
    a = __builtin_bit_cast(float, u << 16);
    b = __builtin_bit_cast(float, u & 0xffff0000u);
}

// -------- prep: dwn weights -> bf16 [co=128][k=256]; smooth -> bf16 [kc][tap][co][32];
//          also zero the softmax-sum accumulator (ws is poisoned each call).
__global__ void prep_kernel(const float* __restrict__ dwn_w,
                            const float* __restrict__ smooth_w,
                            unsigned short* __restrict__ Wd, unsigned short* __restrict__ Wbf,
                            float* __restrict__ Ssum) {
    int idx = blockIdx.x * 256 + threadIdx.x;
    if (blockIdx.x == 0 && threadIdx.x < 256) { Ssum[threadIdx.x] = 0.f; Ssum[256 + threadIdx.x] = 0.f; }
    if (idx < 128 * 256) {
        int co = idx >> 8, k = idx & 255;
        int i = co >> 3, f = co & 7;
        Wd[idx] = f2bf(dwn_w[(i * 256 + k) * 8 + f]);     // dwn_w [ND][1][1][C][DF]
    }
    int idx2 = idx - 128 * 256;
    if (idx2 >= 0 && idx2 < 12 * 9 * 256 * 32) {
        int k = idx2 & 31;
        int t = idx2 >> 5;
        int co = t & 255;
        int t2 = t >> 8;
        int tap = t2 % 9;
        int kc = t2 / 9;
        int ci = kc * 32 + k;
        Wbf[idx2] = f2bf(smooth_w[(tap * 384 + ci) * 256 + co]); // smooth_w [3][3][CAT][C]
    }
}

// -------- K1: input LN -> bf16 cat[:,0:256] ----------------------------------------
__global__ void ln_in_kernel(const float* __restrict__ x, const float* __restrict__ g,
                             const float* __restrict__ b, unsigned short* __restrict__ cat) {
    int wid = threadIdx.x >> 6, lane = threadIdx.x & 63;
    int pix = blockIdx.x * 4 + wid;
    float4 v = ((const float4*)(x + (size_t)pix * CC))[lane];
    float s = v.x + v.y + v.z + v.w;
    float ss = v.x * v.x + v.y * v.y + v.z * v.z + v.w * v.w;
    #pragma unroll
    for (int m = 1; m < 64; m <<= 1) { s += __shfl_xor(s, m); ss += __shfl_xor(ss, m); }
    float mean = s * (1.f / 256.f);
    float rstd = rsqrtf(ss * (1.f / 256.f) - mean * mean + LNEPS);
    float4 gv = ((const float4*)g)[lane];
    float4 bv = ((const float4*)b)[lane];
    float4 y;
    y.x = (v.x - mean) * rstd * gv.x + bv.x;
    y.y = (v.y - mean) * rstd * gv.y + bv.y;
    y.z = (v.z - mean) * rstd * gv.z + bv.z;
    y.w = (v.w - mean) * rstd * gv.w + bv.w;
    ushort4* cp = (ushort4*)(cat + (size_t)pix * CATC + lane * 4);
    *cp = make_ushort4(f2bf(y.x), f2bf(y.y), f2bf(y.z), f2bf(y.w));
}

// -------- K2: dwn 1x1 conv bf16 MFMA GEMM; writes TRANSPOSED dxb_t[i][pix][8] -------
__global__ __launch_bounds__(256)
void dwn_mfma_kernel(const unsigned short* __restrict__ cat, const unsigned short* __restrict__ Wd,
                     const float* __restrict__ dwn_b, unsigned short* __restrict__ dxb_t) {
    __shared__ unsigned short Alds[128 * 40];
    int tid = threadIdx.x;
    int wv = tid >> 6, lane = tid & 63;
    int ml = lane & 15, quad = lane >> 4;
    int pb = blockIdx.x * 128;
    f32x4 acc[8][2];
    #pragma unroll
    for (int mi = 0; mi < 8; mi++)
        #pragma unroll
        for (int ni = 0; ni < 2; ni++) acc[mi][ni] = (f32x4){0.f, 0.f, 0.f, 0.f};

    for (int kc = 0; kc < 8; kc++) {
        __syncthreads();
        #pragma unroll
        for (int it = 0; it < 2; it++) {
            int idx = it * 256 + tid;
            int p = idx >> 2, sub = idx & 3;
            uint4 av = *(const uint4*)(cat + (size_t)(pb + p) * CATC + kc * 32 + sub * 8);
            *(uint4*)&Alds[p * 40 + sub * 8] = av;
        }
        __syncthreads();
        bf16x8 bv[2];
        #pragma unroll
        for (int ni = 0; ni < 2; ni++) {
            int co = wv * 32 + ni * 16 + ml;
            bv[ni] = *(const bf16x8*)(Wd + (size_t)co * 256 + kc * 32 + quad * 8);
        }
        bf16x8 af[8];
        #pragma unroll
        for (int mi = 0; mi < 8; mi++)
            af[mi] = *(const bf16x8*)&Alds[(mi * 16 + ml) * 40 + quad * 8];
        #pragma unroll
        for (int mi = 0; mi < 8; mi++)
            #pragma unroll
            for (int ni = 0; ni < 2; ni++)
                acc[mi][ni] = __builtin_amdgcn_mfma_f32_16x16x32_bf16(af[mi], bv[ni], acc[mi][ni], 0, 0, 0);
    }
    float bias[2];
    #pragma unroll
    for (int ni = 0; ni < 2; ni++) bias[ni] = dwn_b[wv * 32 + ni * 16 + ml];
    #pragma unroll
    for (int mi = 0; mi < 8; mi++)
        #pragma unroll
        for (int rg = 0; rg < 4; rg++) {
            int pixel = pb + mi * 16 + quad * 4 + rg;
            #pragma unroll
            for (int ni = 0; ni < 2; ni++) {
                int co = wv * 32 + ni * 16 + ml;
                float v = fmaxf(acc[mi][ni][rg] + bias[ni], 0.f);
                dxb_t[((size_t)(co >> 3) * NPIX + pixel) * 8 + (co & 7)] = f2bf(v);
            }
        }
}

// -------- K3: dilated 3x3 k,q,v convs; coalesced dxb_t; fused sum(exp(kq)) ----------
__global__ __launch_bounds__(256)
void branch_conv_kernel(const unsigned short* __restrict__ dxb_t,
                        const float* __restrict__ k_w, const float* __restrict__ k_b,
                        const float* __restrict__ q_w, const float* __restrict__ q_b,
                        const float* __restrict__ v_w, const float* __restrict__ v_b,
                        float* __restrict__ kq_t, float* __restrict__ vbuf_t,
                        float* __restrict__ Ssum) {
    __shared__ float wk[576], wq[576], wv_[576];
    __shared__ float bk[8], bq[8], bv[8];
    __shared__ float sred[4][8];
    int i = blockIdx.y;
    int tid = threadIdx.x;
    for (int idx = tid; idx < 576; idx += 256) {
        wk[idx] = k_w[i * 576 + idx];
        wq[idx] = q_w[i * 576 + idx];
        wv_[idx] = v_w[i * 576 + idx];
    }
    if (tid < 8) { bk[tid] = k_b[i * 8 + tid]; bq[tid] = q_b[i * 8 + tid]; bv[tid] = v_b[i * 8 + tid]; }
    __syncthreads();

    int pix0 = blockIdx.x * 1024 + tid;     // 4 pixels: pix0 + g*256, same image
    int n = (blockIdx.x * 1024) >> 14;
    int w = pix0 & 127;
    int d = i + 1;
    int h[4];
    #pragma unroll
    for (int g = 0; g < 4; g++) h[g] = ((pix0 + g * 256) & 16383) >> 7;

    float k[4][8], q[4][8], v[4][8];
    #pragma unroll
    for (int g = 0; g < 4; g++)
        #pragma unroll
        for (int f = 0; f < 8; f++) { k[g][f] = bk[f]; q[g][f] = bq[f]; v[g][f] = bv[f]; }

    const unsigned short* dbase = dxb_t + ((size_t)i * NPIX + ((size_t)n << 14)) * 8;

    for (int ty = 0; ty < 3; ty++) {
        for (int tx = 0; tx < 3; tx++) {
            int sxo = w + (tx - 1) * d;
            bool okx = (unsigned)sxo < 128u;
            float a[4][8];
            #pragma unroll
            for (int g = 0; g < 4; g++) {
                int sy = h[g] + (ty - 1) * d;
                bool ok = okx && ((unsigned)sy < 128u);
                int off = ok ? (sy * 128 + sxo) : 0;
                uint4 raw = *(const uint4*)(dbase + (size_t)off * 8);
                if (!ok) raw = make_uint4(0u, 0u, 0u, 0u);
                bfpair(raw.x, a[g][0], a[g][1]); bfpair(raw.y, a[g][2], a[g][3]);
                bfpair(raw.z, a[g][4], a[g][5]); bfpair(raw.w, a[g][6], a[g][7]);
            }
            int wb = (ty * 3 + tx) * 64;
            #pragma unroll
            for (int ci = 0; ci < 8; ci++) {
                float4 k0 = *(const float4*)&wk[wb + ci * 8];
                float4 k1 = *(const float4*)&wk[wb + ci * 8 + 4];
                float4 q0 = *(const float4*)&wq[wb + ci * 8];
                float4 q1 = *(const float4*)&wq[wb + ci * 8 + 4];
                float4 v0 = *(const float4*)&wv_[wb + ci * 8];
                float4 v1 = *(const float4*)&wv_[wb + ci * 8 + 4];
                #pragma unroll
                for (int g = 0; g < 4; g++) {
                    float xv = a[g][ci];
                    k[g][0] = fmaf(xv, k0.x, k[g][0]); k[g][1] = fmaf(xv, k0.y, k[g][1]);
                    k[g][2] = fmaf(xv, k0.z, k[g][2]); k[g][3] = fmaf(xv, k0.w, k[g][3]);
                    k[g][4] = fmaf(xv, k1.x, k[g][4]); k[g][5] = fmaf(xv, k1.y, k[g][5]);
                    k[g][6] = fmaf(xv, k1.z, k[g][6]); k[g][7] = fmaf(xv, k1.w, k[g][7]);
                    q[g][0] = fmaf(xv, q0.x, q[g][0]); q[g][1] = fmaf(xv, q0.y, q[g][1]);
                    q[g][2] = fmaf(xv, q0.z, q[g][2]); q[g][3] = fmaf(xv, q0.w, q[g][3]);
                    q[g][4] = fmaf(xv, q1.x, q[g][4]); q[g][5] = fmaf(xv, q1.y, q[g][5]);
                    q[g][6] = fmaf(xv, q1.z, q[g][6]); q[g][7] = fmaf(xv, q1.w, q[g][7]);
                    v[g][0] = fmaf(xv, v0.x, v[g][0]); v[g][1] = fmaf(xv, v0.y, v[g][1]);
                    v[g][2] = fmaf(xv, v0.z, v[g][2]); v[g][3] = fmaf(xv, v0.w, v[g][3]);
                    v[g][4] = fmaf(xv, v1.x, v[g][4]); v[g][5] = fmaf(xv, v1.y, v[g][5]);
                    v[g][6] = fmaf(xv, v1.z, v[g][6]); v[g][7] = fmaf(xv, v1.w, v[g][7]);
                }
            }
        }
    }
    // stores + exp partial sums (softmax without max-sub: kq>=0 and small -> exact)
    float es[8];
    #pragma unroll
    for (int f = 0; f < 8; f++) es[f] = 0.f;
    #pragma unroll
    for (int g = 0; g < 4; g++) {
        int pix = pix0 + g * 256;
        int hw = pix & 16383;
        #pragma unroll
        for (int f = 0; f < 8; f++) {
            float kq = fmaxf(k[g][f], 0.f) * fmaxf(q[g][f], 0.f);
            kq_t[((size_t)(n * 128 + i * 8 + f) << 14) + hw] = kq;
            es[f] += __expf(kq);
        }
        float4* vp = (float4*)(vbuf_t + ((size_t)i * NPIX + pix) * 8);
        vp[0] = make_float4(fmaxf(v[g][0], 0.f), fmaxf(v[g][1], 0.f), fmaxf(v[g][2], 0.f), fmaxf(v[g][3], 0.f));
        vp[1] = make_float4(fmaxf(v[g][4], 0.f), fmaxf(v[g][5], 0.f), fmaxf(v[g][6], 0.f), fmaxf(v[g][7], 0.f));
    }
    int wid = tid >> 6, lane = tid & 63;
    #pragma unroll
    for (int f = 0; f < 8; f++) {
        float e = es[f];
        #pragma unroll
        for (int msk = 1; msk < 64; msk <<= 1) e += __shfl_xor(e, msk);
        if (lane == 0) sred[wid][f] = e;
    }
    __syncthreads();
    if (tid < 8) {
        float t = sred[0][tid] + sred[1][tid] + sred[2][tid] + sred[3][tid];
        atomicAdd(&Ssum[n * 128 + i * 8 + tid], t);
    }
}

// -------- K5: attn*v + LN(8) -> cat[:,256:384] bf16 --------------------------------
__global__ void branch_out_kernel(const float* __restrict__ kq_t, const float* __restrict__ vbuf_t,
                                  const float* __restrict__ Ssum,
                                  const float* __restrict__ g_up, const float* __restrict__ b_up,
                                  unsigned short* __restrict__ cat) {
    int i = blockIdx.y;
    int pix = blockIdx.x * 256 + threadIdx.x;
    int n = pix >> 14, hw = pix & 16383;
    float va[8];
    *(float4*)&va[0] = *(const float4*)(vbuf_t + ((size_t)i * NPIX + pix) * 8);
    *(float4*)&va[4] = *(const float4*)(vbuf_t + ((size_t)i * NPIX + pix) * 8 + 4);
    float y[8];
    float s = 0.f, ss = 0.f;
    #pragma unroll
    for (int f = 0; f < 8; f++) {
        int r = n * 128 + i * 8 + f;
        float a = __expf(kq_t[((size_t)r << 14) + hw]) / Ssum[r];
        y[f] = a * va[f];
        s += y[f]; ss += y[f] * y[f];
    }
    float m = s * 0.125f;
    float rstd = rsqrtf(ss * 0.125f - m * m + LNEPS);
    unsigned short o[8];
    #pragma unroll
    for (int f = 0; f < 8; f++) o[f] = f2bf((y[f] - m) * rstd * g_up[f] + b_up[f]);
    ushort4* cp = (ushort4*)(cat + (size_t)pix * CATC + 256 + i * 8);
    cp[0] = make_ushort4(o[0], o[1], o[2], o[3]);
    cp[1] = make_ushort4(o[4], o[5], o[6], o[7]);
}

// -------- K6: smooth 3x3 conv (384->256), M=64 tiles (4 blocks/CU), B via L2 --------
__global__ __launch_bounds__(256, 4)
void smooth_ln_kernel(const unsigned short* __restrict__ cat, const unsigned short* __restrict__ Wbf,
                      const float* __restrict__ smooth_b, const float* __restrict__ g_out,
                      const float* __restrict__ b_out, float* __restrict__ out) {
    __shared__ unsigned short Alds[3 * 66 * 40];    // 3 rows x 66 halo-cols x 32ch (pad 40)
    __shared__ float pwave[4][64][2];
    __shared__ float mrs[64][2];
    int tid = threadIdx.x;
    int wv = tid >> 6, lane = tid & 63;
    int ml = lane & 15, quad = lane >> 4;
    int rowid = blockIdx.x >> 1;             // 0..511 : (n,h)
    int w0 = (blockIdx.x & 1) * 64;          // half-row
    int n = rowid >> 7, h0 = rowid & 127;

    float sbias[4], gg[4], bb[4];
    #pragma unroll
    for (int ni = 0; ni < 4; ni++) {
        int co = wv * 64 + ni * 16 + ml;
        sbias[ni] = smooth_b[co]; gg[ni] = g_out[co]; bb[ni] = b_out[co];
    }
    f32x4 acc[4][4];
    #pragma unroll
    for (int mi = 0; mi < 4; mi++)
        #pragma unroll
        for (int ni = 0; ni < 4; ni++) acc[mi][ni] = (f32x4){0.f, 0.f, 0.f, 0.f};

    for (int kc = 0; kc < 12; kc++) {
        __syncthreads();
        // stage 3x66 neighborhood, 32 channels (792 x 16B chunks)
        #pragma unroll
        for (int it = 0; it < 4; it++) {
            int idx = it * 256 + tid;
            if (idx < 792) {
                int r3 = (idx >= 528) ? 2 : ((idx >= 264) ? 1 : 0);
                int rem = idx - r3 * 264;
                int c66 = rem >> 2, sub = rem & 3;
                int srow = h0 + r3 - 1, scol = w0 + c66 - 1;
                uint4 av = make_uint4(0u, 0u, 0u, 0u);
                if ((unsigned)srow < 128u && (unsigned)scol < 128u)
                    av = *(const uint4*)(cat + (size_t)((n << 14) + srow * 128 + scol) * CATC + kc * 32 + sub * 8);
                *(uint4*)&Alds[(r3 * 66 + c66) * 40 + sub * 8] = av;
            }
        }
        __syncthreads();
        #pragma unroll
        for (int tap = 0; tap < 9; tap++) {
            const int dy = tap / 3, dxo = tap % 3;
            bf16x8 bv[4];
            #pragma unroll
            for (int ni = 0; ni < 4; ni++)
                bv[ni] = *(const bf16x8*)(Wbf + ((size_t)((kc * 9 + tap) * 256 + wv * 64 + ni * 16 + ml)) * 32 + quad * 8);
            bf16x8 af[4];
            #pragma unroll
            for (int mi = 0; mi < 4; mi++)
                af[mi] = *(const bf16x8*)&Alds[(dy * 66 + mi * 16 + ml + dxo) * 40 + quad * 8];
            #pragma unroll
            for (int mi = 0; mi < 4; mi++)
                #pragma unroll
                for (int ni = 0; ni < 4; ni++)
                    acc[mi][ni] = __builtin_amdgcn_mfma_f32_16x16x32_bf16(af[mi], bv[ni], acc[mi][ni], 0, 0, 0);
        }
    }
    // fused bias + relu + LN(256) epilogue
    #pragma unroll
    for (int mi = 0; mi < 4; mi++) {
        #pragma unroll
        for (int rg = 0; rg < 4; rg++) {
            float s = 0.f, ss = 0.f;
            #pragma unroll
            for (int ni = 0; ni < 4; ni++) {
                float v = fmaxf(acc[mi][ni][rg] + sbias[ni], 0.f);
                s += v; ss += v * v;
            }
            #pragma unroll
            for (int msk = 1; msk < 16; msk <<= 1) { s += __shfl_xor(s, msk); ss += __shfl_xor(ss, msk); }
            if (ml == 0) {
                int P = mi * 16 + quad * 4 + rg;
                pwave[wv][P][0] = s; pwave[wv][P][1] = ss;
            }
        }
    }
    __syncthreads();
    if (tid < 64) {
        float s = pwave[0][tid][0] + pwave[1][tid][0] + pwave[2][tid][0] + pwave[3][tid][0];
        float ss = pwave[0][tid][1] + pwave[1][tid][1] + pwave[2][tid][1] + pwave[3][tid][1];
        float m = s * (1.f / 256.f);
        mrs[tid][0] = m;
        mrs[tid][1] = rsqrtf(ss * (1.f / 256.f) - m * m + LNEPS);
    }
    __syncthreads();
    #pragma unroll
    for (int mi = 0; mi < 4; mi++) {
        #pragma unroll
        for (int rg = 0; rg < 4; rg++) {
            int P = mi * 16 + quad * 4 + rg;
            float m = mrs[P][0], rs = mrs[P][1];
            #pragma unroll
            for (int ni = 0; ni < 4; ni++) {
                float v = fmaxf(acc[mi][ni][rg] + sbias[ni], 0.f);
                out[(size_t)(rowid * 128 + w0 + P) * 256 + wv * 64 + ni * 16 + ml] = (v - m) * rs * gg[ni] + bb[ni];
            }
        }
    }
}

extern "C" void kernel_launch(void* const* d_in, const int* in_sizes, int n_in,
                              void* d_out, int out_size, void* d_ws, size_t ws_size,
                              hipStream_t stream) {
    const float* x        = (const float*)d_in[0];
    const float* dwn_w    = (const float*)d_in[1];
    const float* dwn_b    = (const float*)d_in[2];
    const float* k_w      = (const float*)d_in[3];
    const float* k_b      = (const float*)d_in[4];
    const float* q_w      = (const float*)d_in[5];
    const float* q_b      = (const float*)d_in[6];
    const float* v_w      = (const float*)d_in[7];
    const float* v_b      = (const float*)d_in[8];
    const float* smooth_w = (const float*)d_in[9];
    const float* smooth_b = (const float*)d_in[10];
    const float* ln_in_g  = (const float*)d_in[11];
    const float* ln_in_b  = (const float*)d_in[12];
    const float* ln_up_g  = (const float*)d_in[13];
    const float* ln_up_b  = (const float*)d_in[14];
    const float* ln_out_g = (const float*)d_in[15];
    const float* ln_out_b = (const float*)d_in[16];

    char* ws = (char*)d_ws;
    unsigned short* dxb_t  = (unsigned short*)(ws);                // 16 MB
    float*          kq_t   = (float*)(ws + 16777216);              // 32 MB
    float*          vbuf_t = (float*)(ws + 50331648);              // 32 MB
    unsigned short* cat    = (unsigned short*)(ws + 83886080);     // 48 MB
    float*          Ssum   = (float*)(ws + 134217728);             // 2 KB
    unsigned short* Wd     = (unsigned short*)(ws + 134221824);    // 64 KB
    unsigned short* Wbf    = (unsigned short*)(ws + 134287360);    // 1.7 MB
    float* out = (float*)d_out;

    prep_kernel<<<3584, 256, 0, stream>>>(dwn_w, smooth_w, Wd, Wbf, Ssum);
    ln_in_kernel<<<16384, 256, 0, stream>>>(x, ln_in_g, ln_in_b, cat);
    dwn_mfma_kernel<<<512, 256, 0, stream>>>(cat, Wd, dwn_b, dxb_t);
    branch_conv_kernel<<<dim3(64, 16), 256, 0, stream>>>(dxb_t, k_w, k_b, q_w, q_b, v_w, v_b, kq_t, vbuf_t, Ssum);
    branch_out_kernel<<<dim3(256, 16), 256, 0, stream>>>(kq_t, vbuf_t, Ssum, ln_up_g, ln_up_b, cat);
    smooth_ln_kernel<<<1024, 256, 0, stream>>>(cat, Wbf, smooth_b, ln_out_g, ln_out_b, out);
}

// Round 5
// 334.086 us; speedup vs baseline: 1.1428x; 1.1428x over previous
//
#include <hip/hip_runtime.h>
#include <hip/hip_bf16.h>

#define HW 16384
#define NPIX 65536
#define CC 256
#define NDIL 16
#define DFF 8
#define CATC 384
#define LNEPS 1e-3f

typedef short bf16x8 __attribute__((ext_vector_type(8)));
typedef float f32x4 __attribute__((ext_vector_type(4)));

__device__ __forceinline__ unsigned short f2bf(float f) {
    unsigned u = __builtin_bit_cast(unsigned, f);
    u += 0x7fffu + ((u >> 16) & 1u);
    return (unsigned short)(u >> 16);
}

// -------- prep: Wd (dwn bf16 [co][k]); Wbf (smooth bf16 [kc][tap][co][32]);
//          Wb3 (branch kqv bf16 MFMA-B [i][kc3][nt2][ncol16][quad4][j8]); zero Ssum.
__global__ void prep_kernel(const float* __restrict__ dwn_w,
                            const float* __restrict__ smooth_w,
                            const float* __restrict__ k_w, const float* __restrict__ q_w,
                            const float* __restrict__ v_w,
                            unsigned short* __restrict__ Wd, unsigned short* __restrict__ Wbf,
                            unsigned short* __restrict__ Wb3, float* __restrict__ Ssum) {
    int idx = blockIdx.x * 256 + threadIdx.x;
    if (blockIdx.x == 0 && threadIdx.x < 256) { Ssum[threadIdx.x] = 0.f; Ssum[256 + threadIdx.x] = 0.f; }
    if (idx < 128 * 256) {
        int co = idx >> 8, k = idx & 255;
        int i = co >> 3, f = co & 7;
        Wd[idx] = f2bf(dwn_w[(i * 256 + k) * 8 + f]);     // dwn_w [ND][1][1][C][DF]
    }
    int idx2 = idx - 128 * 256;
    if (idx2 >= 0 && idx2 < 12 * 9 * 256 * 32) {
        int k = idx2 & 31;
        int t = idx2 >> 5;
        int co = t & 255;
        int t2 = t >> 8;
        int tap = t2 % 9;
        int kc = t2 / 9;
        int ci = kc * 32 + k;
        Wbf[idx2] = f2bf(smooth_w[(tap * 384 + ci) * 256 + co]); // smooth_w [3][3][CAT][C]
    }
    int idx3 = idx - (128 * 256 + 12 * 9 * 256 * 32);
    if (idx3 >= 0 && idx3 < 16 * 3072) {
        int i = idx3 / 3072, r = idx3 % 3072;
        int kc = r >> 10; r &= 1023;
        int nt = r >> 9;  r &= 511;
        int ncol = r >> 5; r &= 31;
        int quad = r >> 3;
        int j = r & 7;
        int tap = kc * 4 + quad;
        int n = nt * 16 + ncol;
        float val = 0.f;
        if (tap <= 8 && n < 24) {
            int f = n & 7;
            int src = (i * 9 + tap) * 64 + j * 8 + f;    // [ND][3][3][DF][DF]
            val = (n < 8) ? k_w[src] : (n < 16 ? q_w[src] : v_w[src]);
        }
        Wb3[idx3] = f2bf(val);
    }
}

// -------- K1: input LN -> bf16 cat[:,0:256] ----------------------------------------
__global__ void ln_in_kernel(const float* __restrict__ x, const float* __restrict__ g,
                             const float* __restrict__ b, unsigned short* __restrict__ cat) {
    int wid = threadIdx.x >> 6, lane = threadIdx.x & 63;
    int pix = blockIdx.x * 4 + wid;
    float4 v = ((const float4*)(x + (size_t)pix * CC))[lane];
    float s = v.x + v.y + v.z + v.w;
    float ss = v.x * v.x + v.y * v.y + v.z * v.z + v.w * v.w;
    #pragma unroll
    for (int m = 1; m < 64; m <<= 1) { s += __shfl_xor(s, m); ss += __shfl_xor(ss, m); }
    float mean = s * (1.f / 256.f);
    float rstd = rsqrtf(ss * (1.f / 256.f) - mean * mean + LNEPS);
    float4 gv = ((const float4*)g)[lane];
    float4 bv = ((const float4*)b)[lane];
    float4 y;
    y.x = (v.x - mean) * rstd * gv.x + bv.x;
    y.y = (v.y - mean) * rstd * gv.y + bv.y;
    y.z = (v.z - mean) * rstd * gv.z + bv.z;
    y.w = (v.w - mean) * rstd * gv.w + bv.w;
    ushort4* cp = (ushort4*)(cat + (size_t)pix * CATC + lane * 4);
    *cp = make_ushort4(f2bf(y.x), f2bf(y.y), f2bf(y.z), f2bf(y.w));
}

// -------- K2: dwn 1x1 conv bf16 MFMA GEMM; writes TRANSPOSED dxb_t[i][pix][8] -------
__global__ __launch_bounds__(256)
void dwn_mfma_kernel(const unsigned short* __restrict__ cat, const unsigned short* __restrict__ Wd,
                     const float* __restrict__ dwn_b, unsigned short* __restrict__ dxb_t) {
    __shared__ unsigned short Alds[128 * 40];
    int tid = threadIdx.x;
    int wv = tid >> 6, lane = tid & 63;
    int ml = lane & 15, quad = lane >> 4;
    int pb = blockIdx.x * 128;
    f32x4 acc[8][2];
    #pragma unroll
    for (int mi = 0; mi < 8; mi++)
        #pragma unroll
        for (int ni = 0; ni < 2; ni++) acc[mi][ni] = (f32x4){0.f, 0.f, 0.f, 0.f};

    for (int kc = 0; kc < 8; kc++) {
        __syncthreads();
        #pragma unroll
        for (int it = 0; it < 2; it++) {
            int idx = it * 256 + tid;
            int p = idx >> 2, sub = idx & 3;
            uint4 av = *(const uint4*)(cat + (size_t)(pb + p) * CATC + kc * 32 + sub * 8);
            *(uint4*)&Alds[p * 40 + sub * 8] = av;
        }
        __syncthreads();
        bf16x8 bv[2];
        #pragma unroll
        for (int ni = 0; ni < 2; ni++) {
            int co = wv * 32 + ni * 16 + ml;
            bv[ni] = *(const bf16x8*)(Wd + (size_t)co * 256 + kc * 32 + quad * 8);
        }
        bf16x8 af[8];
        #pragma unroll
        for (int mi = 0; mi < 8; mi++)
            af[mi] = *(const bf16x8*)&Alds[(mi * 16 + ml) * 40 + quad * 8];
        #pragma unroll
        for (int mi = 0; mi < 8; mi++)
            #pragma unroll
            for (int ni = 0; ni < 2; ni++)
                acc[mi][ni] = __builtin_amdgcn_mfma_f32_16x16x32_bf16(af[mi], bv[ni], acc[mi][ni], 0, 0, 0);
    }
    float bias[2];
    #pragma unroll
    for (int ni = 0; ni < 2; ni++) bias[ni] = dwn_b[wv * 32 + ni * 16 + ml];
    #pragma unroll
    for (int mi = 0; mi < 8; mi++)
        #pragma unroll
        for (int rg = 0; rg < 4; rg++) {
            int pixel = pb + mi * 16 + quad * 4 + rg;
            #pragma unroll
            for (int ni = 0; ni < 2; ni++) {
                int co = wv * 32 + ni * 16 + ml;
                float v = fmaxf(acc[mi][ni][rg] + bias[ni], 0.f);
                dxb_t[((size_t)(co >> 3) * NPIX + pixel) * 8 + (co & 7)] = f2bf(v);
            }
        }
}

// -------- K3: branch k,q,v dilated 3x3 convs via MFMA (K=tap*8+ci, N=kq|v) ----------
// block = (one image row, one branch); 4 waves; M=128 px; fused relu(k)relu(q), exp-sum
__global__ __launch_bounds__(256)
void branch_conv_kernel(const unsigned short* __restrict__ dxb_t,
                        const unsigned short* __restrict__ Wb3,
                        const float* __restrict__ k_b, const float* __restrict__ q_b,
                        const float* __restrict__ v_b,
                        float* __restrict__ kq_t, float* __restrict__ vbuf_t,
                        float* __restrict__ Ssum) {
    __shared__ unsigned short Slds[3 * 160 * 8];   // 3 dilated rows x 160 halo cols x 8ch
    __shared__ float sred[4][8];
    int i = blockIdx.y;
    int d = i + 1;
    int rowid = blockIdx.x;                 // 0..511
    int n = rowid >> 7, h = rowid & 127;
    int tid = threadIdx.x;
    int wv = tid >> 6, lane = tid & 63;
    int ml = lane & 15, quad = lane >> 4;

    // stage 3 rows (h-d, h, h+d), cols -d..127+d, zeros outside
    #pragma unroll
    for (int it = 0; it < 2; it++) {
        int idx = it * 256 + tid;
        if (idx < 480) {
            int r3 = (idx >= 320) ? 2 : ((idx >= 160) ? 1 : 0);
            int c = idx - r3 * 160;
            int row = h + (r3 - 1) * d;
            int col = c - d;
            uint4 val = make_uint4(0u, 0u, 0u, 0u);
            if ((unsigned)row < 128u && (unsigned)col < 128u)
                val = *(const uint4*)(dxb_t + ((size_t)(i << 16) + (size_t)((n << 14) + (row << 7) + col)) * 8);
            *(uint4*)&Slds[idx * 8] = val;
        }
    }
    __syncthreads();

    // per-lane tap geometry (clamped; pad taps have B=0)
    int tap0 = quad, tap1 = 4 + quad, tap2 = 8;
    int ty0 = tap0 / 3, tx0 = tap0 % 3;
    int ty1 = tap1 / 3, tx1 = tap1 % 3;
    const int ty2 = 2, tx2 = 2;

    // B fragments (L2-resident)
    const unsigned short* wb = Wb3 + i * 3072 + ml * 32 + quad * 8;
    bf16x8 bfrag[3][2];
    #pragma unroll
    for (int kc = 0; kc < 3; kc++)
        #pragma unroll
        for (int nt = 0; nt < 2; nt++)
            bfrag[kc][nt] = *(const bf16x8*)(wb + kc * 1024 + nt * 512);

    f32x4 acc[2][2];
    #pragma unroll
    for (int mt = 0; mt < 2; mt++)
        #pragma unroll
        for (int nt = 0; nt < 2; nt++) acc[mt][nt] = (f32x4){0.f, 0.f, 0.f, 0.f};

    #pragma unroll
    for (int mt = 0; mt < 2; mt++) {
        int m0 = (wv * 2 + mt) * 16 + ml;
        bf16x8 a0 = *(const bf16x8*)&Slds[(ty0 * 160 + m0 + tx0 * d) * 8];
        bf16x8 a1 = *(const bf16x8*)&Slds[(ty1 * 160 + m0 + tx1 * d) * 8];
        bf16x8 a2 = *(const bf16x8*)&Slds[(ty2 * 160 + m0 + tx2 * d) * 8];
        #pragma unroll
        for (int nt = 0; nt < 2; nt++) {
            acc[mt][nt] = __builtin_amdgcn_mfma_f32_16x16x32_bf16(a0, bfrag[0][nt], acc[mt][nt], 0, 0, 0);
            acc[mt][nt] = __builtin_amdgcn_mfma_f32_16x16x32_bf16(a1, bfrag[1][nt], acc[mt][nt], 0, 0, 0);
            acc[mt][nt] = __builtin_amdgcn_mfma_f32_16x16x32_bf16(a2, bfrag[2][nt], acc[mt][nt], 0, 0, 0);
        }
    }

    // epilogue: bias+relu, kq via shfl, stores, exp-sum
    float bkq = (ml < 8) ? k_b[i * 8 + ml] : q_b[i * 8 + (ml & 7)];
    float bvv = (ml < 8) ? v_b[i * 8 + ml] : 0.f;
    float e = 0.f;
    #pragma unroll
    for (int mt = 0; mt < 2; mt++) {
        #pragma unroll
        for (int rg = 0; rg < 4; rg++) {
            float kx = fmaxf(acc[mt][0][rg] + bkq, 0.f);
            float qx = __shfl_xor(kx, 8);
            float kq = kx * qx;
            float vx = fmaxf(acc[mt][1][rg] + bvv, 0.f);
            int p = (wv * 2 + mt) * 16 + quad * 4 + rg;
            if (ml < 8) {
                int hw = h * 128 + p;
                kq_t[((size_t)(n * 128 + i * 8 + ml) << 14) + hw] = kq;
                vbuf_t[((size_t)(i << 16) + (n << 14) + hw) * 8 + ml] = vx;
                e += __expf(kq);
            }
        }
    }
    e += __shfl_xor(e, 16);
    e += __shfl_xor(e, 32);
    if ((lane >> 4) == 0 && ml < 8) sred[wv][ml] = e;
    __syncthreads();
    if (tid < 8) {
        float t = sred[0][tid] + sred[1][tid] + sred[2][tid] + sred[3][tid];
        atomicAdd(&Ssum[n * 128 + i * 8 + tid], t);
    }
}

// -------- K5: attn*v + LN(8) -> cat[:,256:384] bf16 --------------------------------
__global__ void branch_out_kernel(const float* __restrict__ kq_t, const float* __restrict__ vbuf_t,
                                  const float* __restrict__ Ssum,
                                  const float* __restrict__ g_up, const float* __restrict__ b_up,
                                  unsigned short* __restrict__ cat) {
    int i = blockIdx.y;
    int pix = blockIdx.x * 256 + threadIdx.x;
    int n = pix >> 14, hw = pix & 16383;
    float va[8];
    *(float4*)&va[0] = *(const float4*)(vbuf_t + ((size_t)i * NPIX + pix) * 8);
    *(float4*)&va[4] = *(const float4*)(vbuf_t + ((size_t)i * NPIX + pix) * 8 + 4);
    float y[8];
    float s = 0.f, ss = 0.f;
    #pragma unroll
    for (int f = 0; f < 8; f++) {
        int r = n * 128 + i * 8 + f;
        float a = __expf(kq_t[((size_t)r << 14) + hw]) / Ssum[r];
        y[f] = a * va[f];
        s += y[f]; ss += y[f] * y[f];
    }
    float m = s * 0.125f;
    float rstd = rsqrtf(ss * 0.125f - m * m + LNEPS);
    unsigned short o[8];
    #pragma unroll
    for (int f = 0; f < 8; f++) o[f] = f2bf((y[f] - m) * rstd * g_up[f] + b_up[f]);
    ushort4* cp = (ushort4*)(cat + (size_t)pix * CATC + 256 + i * 8);
    cp[0] = make_ushort4(o[0], o[1], o[2], o[3]);
    cp[1] = make_ushort4(o[4], o[5], o[6], o[7]);
}

// -------- K6: smooth 3x3 conv (384->256), M=128 row, neighborhood LDS, B via L2 -----
__global__ __launch_bounds__(256, 2)
void smooth_ln_kernel(const unsigned short* __restrict__ cat, const unsigned short* __restrict__ Wbf,
                      const float* __restrict__ smooth_b, const float* __restrict__ g_out,
                      const float* __restrict__ b_out, float* __restrict__ out) {
    __shared__ unsigned short Alds[3 * 130 * 40];   // 3 rows x 130 halo-cols x 32ch (pad 40)
    __shared__ float pwave[4][128][2];
    __shared__ float mrs[128][2];
    int tid = threadIdx.x;
    int wv = tid >> 6, lane = tid & 63;
    int ml = lane & 15, quad = lane >> 4;
    int rowid = blockIdx.x;                  // 0..511 : (n,h)
    int n = rowid >> 7, h0 = rowid & 127;
    int pb = rowid * 128;                    // first pixel of this row

    float sbias[4], gg[4], bb[4];
    #pragma unroll
    for (int ni = 0; ni < 4; ni++) {
        int co = wv * 64 + ni * 16 + ml;
        sbias[ni] = smooth_b[co]; gg[ni] = g_out[co]; bb[ni] = b_out[co];
    }
    f32x4 acc[8][4];
    #pragma unroll
    for (int mi = 0; mi < 8; mi++)
        #pragma unroll
        for (int ni = 0; ni < 4; ni++) acc[mi][ni] = (f32x4){0.f, 0.f, 0.f, 0.f};

    for (int kc = 0; kc < 12; kc++) {
        __syncthreads();
        // stage 3x130 neighborhood, 32 channels
        for (int it = 0; it < 7; it++) {
            int idx = it * 256 + tid;
            if (idx < 1560) {
                int r3 = (idx >= 1040) ? 2 : ((idx >= 520) ? 1 : 0);
                int rem = idx - r3 * 520;
                int c130 = rem >> 2, sub = rem & 3;
                int srow = h0 + r3 - 1, scol = c130 - 1;
                uint4 av = make_uint4(0u, 0u, 0u, 0u);
                if ((unsigned)srow < 128u && (unsigned)scol < 128u)
                    av = *(const uint4*)(cat + (size_t)((n << 14) + srow * 128 + scol) * CATC + kc * 32 + sub * 8);
                *(uint4*)&Alds[(r3 * 130 + c130) * 40 + sub * 8] = av;
            }
        }
        __syncthreads();
        #pragma unroll
        for (int tap = 0; tap < 9; tap++) {
            const int dy = tap / 3, dxo = tap % 3;
            bf16x8 bv[4];
            #pragma unroll
            for (int ni = 0; ni < 4; ni++)
                bv[ni] = *(const bf16x8*)(Wbf + ((size_t)((kc * 9 + tap) * 256 + wv * 64 + ni * 16 + ml)) * 32 + quad * 8);
            bf16x8 af[8];
            #pragma unroll
            for (int mi = 0; mi < 8; mi++)
                af[mi] = *(const bf16x8*)&Alds[(dy * 130 + mi * 16 + ml + dxo) * 40 + quad * 8];
            #pragma unroll
            for (int mi = 0; mi < 8; mi++)
                #pragma unroll
                for (int ni = 0; ni < 4; ni++)
                    acc[mi][ni] = __builtin_amdgcn_mfma_f32_16x16x32_bf16(af[mi], bv[ni], acc[mi][ni], 0, 0, 0);
        }
    }
    // fused bias + relu + LN(256) epilogue
    #pragma unroll
    for (int mi = 0; mi < 8; mi++) {
        #pragma unroll
        for (int rg = 0; rg < 4; rg++) {
            float s = 0.f, ss = 0.f;
            #pragma unroll
            for (int ni = 0; ni < 4; ni++) {
                float v = fmaxf(acc[mi][ni][rg] + sbias[ni], 0.f);
                s += v; ss += v * v;
            }
            #pragma unroll
            for (int msk = 1; msk < 16; msk <<= 1) { s += __shfl_xor(s, msk); ss += __shfl_xor(ss, msk); }
            if (ml == 0) {
                int P = mi * 16 + quad * 4 + rg;
                pwave[wv][P][0] = s; pwave[wv][P][1] = ss;
            }
        }
    }
    __syncthreads();
    if (tid < 128) {
        float s = pwave[0][tid][0] + pwave[1][tid][0] + pwave[2][tid][0] + pwave[3][tid][0];
        float ss = pwave[0][tid][1] + pwave[1][tid][1] + pwave[2][tid][1] + pwave[3][tid][1];
        float m = s * (1.f / 256.f);
        mrs[tid][0] = m;
        mrs[tid][1] = rsqrtf(ss * (1.f / 256.f) - m * m + LNEPS);
    }
    __syncthreads();
    #pragma unroll
    for (int mi = 0; mi < 8; mi++) {
        #pragma unroll
        for (int rg = 0; rg < 4; rg++) {
            int P = mi * 16 + quad * 4 + rg;
            float m = mrs[P][0], rs = mrs[P][1];
            #pragma unroll
            for (int ni = 0; ni < 4; ni++) {
                float v = fmaxf(acc[mi][ni][rg] + sbias[ni], 0.f);
                out[(size_t)(pb + P) * 256 + wv * 64 + ni * 16 + ml] = (v - m) * rs * gg[ni] + bb[ni];
            }
        }
    }
}

extern "C" void kernel_launch(void* const* d_in, const int* in_sizes, int n_in,
                              void* d_out, int out_size, void* d_ws, size_t ws_size,
                              hipStream_t stream) {
    const float* x        = (const float*)d_in[0];
    const float* dwn_w    = (const float*)d_in[1];
    const float* dwn_b    = (const float*)d_in[2];
    const float* k_w      = (const float*)d_in[3];
    const float* k_b      = (const float*)d_in[4];
    const float* q_w      = (const float*)d_in[5];
    const float* q_b      = (const float*)d_in[6];
    const float* v_w      = (const float*)d_in[7];
    const float* v_b      = (const float*)d_in[8];
    const float* smooth_w = (const float*)d_in[9];
    const float* smooth_b = (const float*)d_in[10];
    const float* ln_in_g  = (const float*)d_in[11];
    const float* ln_in_b  = (const float*)d_in[12];
    const float* ln_up_g  = (const float*)d_in[13];
    const float* ln_up_b  = (const float*)d_in[14];
    const float* ln_out_g = (const float*)d_in[15];
    const float* ln_out_b = (const float*)d_in[16];

    char* ws = (char*)d_ws;
    unsigned short* dxb_t  = (unsigned short*)(ws);                // 16 MB
    float*          kq_t   = (float*)(ws + 16777216);              // 32 MB
    float*          vbuf_t = (float*)(ws + 50331648);              // 32 MB
    unsigned short* cat    = (unsigned short*)(ws + 83886080);     // 48 MB
    float*          Ssum   = (float*)(ws + 134217728);             // 2 KB
    unsigned short* Wd     = (unsigned short*)(ws + 134221824);    // 64 KB
    unsigned short* Wbf    = (unsigned short*)(ws + 134287360);    // 1.73 MB
    unsigned short* Wb3    = (unsigned short*)(ws + 136056832);    // 96 KB
    float* out = (float*)d_out;

    prep_kernel<<<3776, 256, 0, stream>>>(dwn_w, smooth_w, k_w, q_w, v_w, Wd, Wbf, Wb3, Ssum);
    ln_in_kernel<<<16384, 256, 0, stream>>>(x, ln_in_g, ln_in_b, cat);
    dwn_mfma_kernel<<<512, 256, 0, stream>>>(cat, Wd, dwn_b, dxb_t);
    branch_conv_kernel<<<dim3(512, 16), 256, 0, stream>>>(dxb_t, Wb3, k_b, q_b, v_b, kq_t, vbuf_t, Ssum);
    branch_out_kernel<<<dim3(256, 16), 256, 0, stream>>>(kq_t, vbuf_t, Ssum, ln_up_g, ln_up_b, cat);
    smooth_ln_kernel<<<512, 256, 0, stream>>>(cat, Wbf, smooth_b, ln_out_g, ln_out_b, out);
}